// Round 1
// baseline (26.407 us; speedup 1.0000x reference)
//
#include <hip/hip_runtime.h>
#include <math.h>

// Problem constants (match reference)
constexpr int B_ = 8;
constexpr int N_ = 128;
constexpr int H_ = 256;
constexpr int W_ = 256;
constexpr int PIX_PER_BATCH = H_ * W_;          // 65536
constexpr int BLOCK = 256;
constexpr int BLOCKS_PER_BATCH = PIX_PER_BATCH / BLOCK;  // 256

__global__ __launch_bounds__(BLOCK) void gaussian_vorticity_kernel(
    const float* __restrict__ vf,   // [B, N, 4] = (y, x, tau, sigma)
    const float* __restrict__ pts,  // [B, H, W, 2]
    float* __restrict__ out)        // [B, H, W, 1]
{
    __shared__ float4 sv[N_];  // (y, x, a=-log2e/sig2, c=tau/(pi*sig2))

    const int b = blockIdx.x / BLOCKS_PER_BATCH;
    const int pixInBatch = (blockIdx.x % BLOCKS_PER_BATCH) * BLOCK + threadIdx.x;

    // Stage transformed vortex params into LDS (first 128 threads)
    if (threadIdx.x < N_) {
        const float4 v = reinterpret_cast<const float4*>(vf)[b * N_ + threadIdx.x];
        const float y = v.x, x = v.y, tau = v.z, sig = v.w;
        const float inv_sig2 = 1.0f / (sig * sig);
        const float a = -1.4426950408889634f * inv_sig2;       // -log2(e)/sig^2
        const float c = tau * 0.3183098861837907f * inv_sig2;  // tau/(pi*sig^2)
        sv[threadIdx.x] = make_float4(y, x, a, c);
    }
    __syncthreads();

    const float2 p = reinterpret_cast<const float2*>(
        pts + (size_t)b * PIX_PER_BATCH * 2)[pixInBatch];

    float acc = 0.0f;
#pragma unroll 8
    for (int n = 0; n < N_; ++n) {
        const float4 v = sv[n];
        const float dy = p.x - v.x;
        const float dx = p.y - v.y;
        const float sq = dy * dy + dx * dx;
        acc += exp2f(sq * v.z) * v.w;   // exp(-sq/sig2) / (pi*sig2) * tau
    }

    out[(size_t)b * PIX_PER_BATCH + pixInBatch] = acc;
}

extern "C" void kernel_launch(void* const* d_in, const int* in_sizes, int n_in,
                              void* d_out, int out_size, void* d_ws, size_t ws_size,
                              hipStream_t stream) {
    const float* vf  = (const float*)d_in[0];   // [B, N, 4]
    const float* pts = (const float*)d_in[1];   // [B, H, W, 2]
    float* out = (float*)d_out;                 // [B, H, W, 1]

    const int grid = B_ * BLOCKS_PER_BATCH;     // 2048 blocks
    gaussian_vorticity_kernel<<<grid, BLOCK, 0, stream>>>(vf, pts, out);
}

// Round 2
// 20.273 us; speedup vs baseline: 1.3026x; 1.3026x over previous
//
#include <hip/hip_runtime.h>
#include <math.h>

// Problem constants (match reference)
constexpr int B_ = 8;
constexpr int N_ = 128;
constexpr int H_ = 256;
constexpr int W_ = 256;
constexpr int PIX = H_ * W_;                       // 65536 pixels per batch
constexpr int BLOCK = 256;
constexpr int PIX_PER_THREAD = 4;                  // amortize LDS read over 4 pixels
constexpr int PIX_PER_BLOCK = BLOCK * PIX_PER_THREAD;   // 1024
constexpr int BLOCKS_PER_BATCH = PIX / PIX_PER_BLOCK;   // 64

__global__ __launch_bounds__(BLOCK) void gaussian_vorticity_kernel(
    const float* __restrict__ vf,   // [B, N, 4] = (y, x, tau, sigma)
    const float* __restrict__ pts,  // [B, H, W, 2]
    float* __restrict__ out)        // [B, H, W, 1]
{
    __shared__ float4 sv[N_];  // (y, x, a=-log2e/sig2, c=tau/(pi*sig2))

    const int b = blockIdx.x / BLOCKS_PER_BATCH;
    const int blkPix = (blockIdx.x % BLOCKS_PER_BATCH) * PIX_PER_BLOCK;
    const int t = threadIdx.x;

    // Stage transformed vortex params into LDS (first 128 threads)
    if (t < N_) {
        const float4 v = reinterpret_cast<const float4*>(vf)[b * N_ + t];
        const float y = v.x, x = v.y, tau = v.z, sig = v.w;
        const float inv_sig2 = 1.0f / (sig * sig);
        const float a = -1.4426950408889634f * inv_sig2;       // -log2(e)/sig^2
        const float c = tau * 0.3183098861837907f * inv_sig2;  // tau/(pi*sig^2)
        sv[t] = make_float4(y, x, a, c);
    }
    __syncthreads();

    // Each thread owns 4 pixels: (2t, 2t+1) and (2t+512, 2t+513) within the
    // block's 1024-pixel span. float4 = 2 consecutive (y,x) points.
    const float4* pbase = reinterpret_cast<const float4*>(
        pts + (size_t)b * PIX * 2) + (blkPix >> 1);
    const float4 p01 = pbase[t];            // pixels 2t, 2t+1
    const float4 p23 = pbase[t + BLOCK];    // pixels 2t+512, 2t+513

    float acc0 = 0.0f, acc1 = 0.0f, acc2 = 0.0f, acc3 = 0.0f;
#pragma unroll 4
    for (int n = 0; n < N_; ++n) {
        const float4 v = sv[n];  // one ds_read_b128, reused for 4 pixels
        {
            const float dy = p01.x - v.x, dx = p01.y - v.y;
            acc0 += __builtin_amdgcn_exp2f((dy * dy + dx * dx) * v.z) * v.w;
        }
        {
            const float dy = p01.z - v.x, dx = p01.w - v.y;
            acc1 += __builtin_amdgcn_exp2f((dy * dy + dx * dx) * v.z) * v.w;
        }
        {
            const float dy = p23.x - v.x, dx = p23.y - v.y;
            acc2 += __builtin_amdgcn_exp2f((dy * dy + dx * dx) * v.z) * v.w;
        }
        {
            const float dy = p23.z - v.x, dx = p23.w - v.y;
            acc3 += __builtin_amdgcn_exp2f((dy * dy + dx * dx) * v.z) * v.w;
        }
    }

    float2* ob = reinterpret_cast<float2*>(out + (size_t)b * PIX + blkPix);
    ob[t]         = make_float2(acc0, acc1);
    ob[t + BLOCK] = make_float2(acc2, acc3);
}

extern "C" void kernel_launch(void* const* d_in, const int* in_sizes, int n_in,
                              void* d_out, int out_size, void* d_ws, size_t ws_size,
                              hipStream_t stream) {
    const float* vf  = (const float*)d_in[0];   // [B, N, 4]
    const float* pts = (const float*)d_in[1];   // [B, H, W, 2]
    float* out = (float*)d_out;                 // [B, H, W, 1]

    const int grid = B_ * BLOCKS_PER_BATCH;     // 512 blocks
    gaussian_vorticity_kernel<<<grid, BLOCK, 0, stream>>>(vf, pts, out);
}